// Round 13
// baseline (280.194 us; speedup 1.0000x reference)
//
#include <hip/hip_runtime.h>
#include <hip/hip_bf16.h>

#define EPSV 1e-5f
#define BKT 128            // nodes per bucket
#define NB  782            // ceil(100000/128)
#define LPK 4096           // LDS pk cache per bucket (mean 2048, +45 sigma safe)

typedef __hip_bfloat16 bf16;
typedef __attribute__((ext_vector_type(8))) short short8v;
typedef __attribute__((ext_vector_type(4))) float f32x4v;

__device__ inline void atomAddG(float* p, float v) { unsafeAtomicAdd(p, v); }
__device__ inline unsigned short f2bf(float v) {
    bf16 h = __float2bfloat16(v);
    return *reinterpret_cast<unsigned short*>(&h);
}
__device__ inline float bfu(unsigned short u) {
    return __uint_as_float(((unsigned int)u) << 16);
}

// ---- bucket histogram (782 bins) + fused xpad + fused graph-bounds ----
__global__ __launch_bounds__(256) void bhist_kernel(
    const int* __restrict__ edges, int* __restrict__ gbcnt,
    const float* __restrict__ x, float* __restrict__ xp,
    const int* __restrict__ membership, int* __restrict__ gstart, int E, int N)
{
    __shared__ int lh[NB];
    const int t = threadIdx.x;
    for (int i = t; i < NB; i += 256) lh[i] = 0;
    // fused xpad + bounds: this grid (391x256 = 100096) covers N+1
    {
        int n = blockIdx.x * 256 + t;
        if (n < N) {
            float4 v;
            v.x = x[n * 3 + 0]; v.y = x[n * 3 + 1]; v.z = x[n * 3 + 2]; v.w = 0.f;
            *(float4*)&xp[n * 4] = v;
        }
        if (n <= N) {
            int mp = (n == 0) ? -1 : membership[n - 1];
            int mc = (n == N) ? 64 : membership[n];
            for (int g = mp + 1; g <= mc; ++g) gstart[g] = n;
        }
    }
    __syncthreads();
    const int base = blockIdx.x * 4096;
    #pragma unroll
    for (int i = 0; i < 16; ++i) {
        int e = base + i * 256 + t;
        if (e < E) atomicAdd(&lh[edges[E + e] >> 7], 1);
    }
    __syncthreads();
    for (int i = t; i < NB; i += 256) {
        int c = lh[i];
        if (c) atomicAdd(&gbcnt[i], c);
    }
}

// ------- bucket scan (single block): bbase exclusive + cursor copy -------
__global__ __launch_bounds__(256) void bscan_kernel(
    const int* __restrict__ gbcnt, int* __restrict__ bbase,
    int* __restrict__ gcursor, int E)
{
    __shared__ int l[256];
    const int t = threadIdx.x;
    int b0 = t * 4;
    int v0 = (b0 + 0 < NB) ? gbcnt[b0 + 0] : 0;
    int v1 = (b0 + 1 < NB) ? gbcnt[b0 + 1] : 0;
    int v2 = (b0 + 2 < NB) ? gbcnt[b0 + 2] : 0;
    int v3 = (b0 + 3 < NB) ? gbcnt[b0 + 3] : 0;
    int tot = v0 + v1 + v2 + v3;
    l[t] = tot;
    __syncthreads();
    for (int o = 1; o < 256; o <<= 1) {
        int add = (t >= o) ? l[t - o] : 0;
        __syncthreads();
        l[t] += add;
        __syncthreads();
    }
    int off = l[t] - tot;
    if (b0 + 0 < NB) { bbase[b0 + 0] = off;                gcursor[b0 + 0] = off; }
    if (b0 + 1 < NB) { bbase[b0 + 1] = off + v0;           gcursor[b0 + 1] = off + v0; }
    if (b0 + 2 < NB) { bbase[b0 + 2] = off + v0 + v1;      gcursor[b0 + 2] = off + v0 + v1; }
    if (b0 + 3 < NB) { bbase[b0 + 3] = off + v0 + v1 + v2; gcursor[b0 + 3] = off + v0 + v1 + v2; }
    if (t == 0) bbase[NB] = E;
}

// ------- bucket fill: pk = (src<<7)|(dst&127), 8192 edges/block -------
__global__ __launch_bounds__(256) void bfill_kernel(
    const int* __restrict__ edges, int* __restrict__ gcursor,
    int* __restrict__ pk, int E)
{
    __shared__ int lh[NB];
    __shared__ int lbase[NB];
    const int t = threadIdx.x;
    for (int i = t; i < NB; i += 256) lh[i] = 0;
    __syncthreads();
    const int base = blockIdx.x * 8192;
    int dv[32];
    #pragma unroll
    for (int i = 0; i < 32; ++i) {
        int e = base + i * 256 + t;
        dv[i] = (e < E) ? edges[E + e] : -1;
        if (dv[i] >= 0) atomicAdd(&lh[dv[i] >> 7], 1);
    }
    __syncthreads();
    for (int i = t; i < NB; i += 256) {
        int c = lh[i];
        lbase[i] = c ? atomicAdd(&gcursor[i], c) : 0;
        lh[i] = 0;
    }
    __syncthreads();
    #pragma unroll
    for (int i = 0; i < 32; ++i) {
        int e = base + i * 256 + t;
        if (dv[i] >= 0) {
            int s = edges[e];
            int b = dv[i] >> 7;
            int pos = lbase[b] + atomicAdd(&lh[b], 1);
            pk[pos] = (s << 7) | (dv[i] & 127);
        }
    }
}

// ---- per-bucket fine sort + fused x-gather + FUSED LAYER 1:
// ---- CSR rowstart + srcs; u1b = bf16(relu(agg@W_rel1+b+x@W_root1)); BN1 stats. ----
__global__ __launch_bounds__(256) void bsort_kernel(
    const int* __restrict__ pk, const int* __restrict__ bbase,
    const float* __restrict__ xp,
    const float* __restrict__ W_rel1, const float* __restrict__ b_rel1,
    const float* __restrict__ W_root1,
    int* __restrict__ rowstart, int* __restrict__ srcs,
    unsigned short* __restrict__ u1b, float* __restrict__ sums, float* __restrict__ sumsq,
    int N, int E)
{
    __shared__ int lcnt[BKT];
    __shared__ int lscan[BKT];
    __shared__ float accx[BKT * 4];
    __shared__ int lpk[LPK];
    __shared__ float red[4][64];
    const int t = threadIdx.x;
    const int b = blockIdx.x;
    const int e0 = bbase[b], e1 = bbase[b + 1];
    const int cnt = e1 - e0;
    if (t < BKT) lcnt[t] = 0;
    for (int i = t; i < BKT * 4; i += 256) accx[i] = 0.f;
    for (int i = t; i < cnt && i < LPK; i += 256) lpk[i] = pk[e0 + i];
    __syncthreads();
    for (int i = t; i < cnt; i += 256) {
        int v = (i < LPK) ? lpk[i] : pk[e0 + i];
        atomicAdd(&lcnt[v & 127], 1);
    }
    __syncthreads();
    if (t < BKT) lscan[t] = lcnt[t];
    __syncthreads();
    for (int o = 1; o < BKT; o <<= 1) {
        int add = (t < BKT && t >= o) ? lscan[t - o] : 0;
        __syncthreads();
        if (t < BKT) lscan[t] += add;
        __syncthreads();
    }
    const int n0 = b * BKT;
    if (t < BKT) {
        int excl = lscan[t] - lcnt[t];
        lscan[t] = excl;
        int n = n0 + t;
        if (n <= N) rowstart[n] = e0 + excl;   // last bucket's t=32 writes rowstart[N]=E
        lcnt[t] = 0;
    }
    __syncthreads();
    for (int i = t; i < cnt; i += 256) {
        int v = (i < LPK) ? lpk[i] : pk[e0 + i];
        int ld = v & 127;
        int s = v >> 7;
        int pos = atomicAdd(&lcnt[ld], 1);
        srcs[e0 + lscan[ld] + pos] = s;
        float4 xv = *(const float4*)&xp[s * 4];
        atomicAdd(&accx[ld * 4 + 0], xv.x);
        atomicAdd(&accx[ld * 4 + 1], xv.y);
        atomicAdd(&accx[ld * 4 + 2], xv.z);
    }
    __syncthreads();

    // fused layer 1: u1 = relu(agg@W_rel1 + b_rel1 + x@W_root1) -> bf16, + stats
    const int f = t & 63, r4 = t >> 6;
    const float wr0 = W_rel1[f], wr1 = W_rel1[64 + f], wr2 = W_rel1[128 + f];
    const float wo0 = W_root1[f], wo1 = W_root1[64 + f], wo2 = W_root1[128 + f];
    const float bb = b_rel1[f];
    float ps = 0.f, pq = 0.f;
    for (int i = r4; i < BKT; i += 4) {
        int n = n0 + i;
        if (n < N) {
            float4 xv = *(const float4*)&xp[n * 4];
            float a0 = accx[i * 4 + 0], a1 = accx[i * 4 + 1], a2 = accx[i * 4 + 2];
            float v = bb;
            v = fmaf(a0, wr0, v); v = fmaf(a1, wr1, v); v = fmaf(a2, wr2, v);
            v = fmaf(xv.x, wo0, v); v = fmaf(xv.y, wo1, v); v = fmaf(xv.z, wo2, v);
            v = fmaxf(v, 0.f);
            u1b[n * 64 + f] = f2bf(v);
            ps += v; pq += v * v;
        }
    }
    red[r4][f] = ps;
    __syncthreads();
    if (r4 == 0) atomAddG(&sums[f], red[0][f] + red[1][f] + red[2][f] + red[3][f]);
    __syncthreads();
    red[r4][f] = pq;
    __syncthreads();
    if (r4 == 0) atomAddG(&sumsq[f], red[0][f] + red[1][f] + red[2][f] + red[3][f]);
}

// ---- fused BN1-stats + weight fold: W' = bf16(diag(sc1)W), c = sh1·W (+b_rel2) ----
__global__ __launch_bounds__(256) void bnfold_kernel(
    const float* __restrict__ sums1, const float* __restrict__ sumsq1,
    const float* __restrict__ g1, const float* __restrict__ b1,
    const float* __restrict__ W_rel2, const float* __restrict__ W_root2,
    const float* __restrict__ b_rel2,
    unsigned short* __restrict__ wrelp, unsigned short* __restrict__ wrootp,
    float* __restrict__ crel, float* __restrict__ croot, float invn)
{
    __shared__ float lsc[64], lsh[64];
    __shared__ float r1[4][64], r2[4][64];
    const int t = threadIdx.x, f = t & 63, kg = t >> 6;
    if (t < 64) {
        float m = sums1[t] * invn;
        float v = sumsq1[t] * invn - m * m;
        float sc = g1[t] * rsqrtf(v + EPSV);
        lsc[t] = sc;
        lsh[t] = b1[t] - m * sc;
    }
    __syncthreads();
    float c1 = 0.f, c2 = 0.f;
    for (int k = kg * 16; k < kg * 16 + 16; ++k) {
        float sc = lsc[k], sh = lsh[k];
        float w1 = W_rel2[k * 64 + f], w2 = W_root2[k * 64 + f];
        wrelp[k * 64 + f] = f2bf(sc * w1);
        wrootp[k * 64 + f] = f2bf(sc * w2);
        c1 = fmaf(sh, w1, c1); c2 = fmaf(sh, w2, c2);
    }
    r1[kg][f] = c1; r2[kg][f] = c2;
    __syncthreads();
    if (kg == 0) {
        crel[f]  = r1[0][f] + r1[1][f] + r1[2][f] + r1[3][f];
        croot[f] = r2[0][f] + r2[1][f] + r2[2][f] + r2[3][f] + b_rel2[f];
    }
}

// ---- MFMA transform: t = bf16(u1b@W_rel' + crel); p = bf16(u1b@W_root' + croot) ----
__global__ __launch_bounds__(256) void mfma_transform_kernel(
    const unsigned short* __restrict__ u1b,
    const unsigned short* __restrict__ wrelp, const unsigned short* __restrict__ wrootp,
    const float* __restrict__ crel, const float* __restrict__ croot,
    unsigned short* __restrict__ tb, unsigned short* __restrict__ pb, int NT)
{
    const int wid = (blockIdx.x * blockDim.x + threadIdx.x) >> 6;
    const int lane = threadIdx.x & 63;
    const int q = lane >> 4, r = lane & 15;

    short8v Bf[2][8];
    float cadd[8];
    #pragma unroll
    for (int kc = 0; kc < 2; ++kc) {
        #pragma unroll
        for (int ft = 0; ft < 8; ++ft) {
            const unsigned short* W = (ft < 4) ? wrelp : wrootp;
            const int f0 = (ft & 3) * 16;
            short8v bb;
            #pragma unroll
            for (int j = 0; j < 8; ++j) {
                int k = 32 * kc + 8 * q + j;
                bb[j] = (short)W[k * 64 + f0 + r];
            }
            Bf[kc][ft] = bb;
        }
    }
    #pragma unroll
    for (int ft = 0; ft < 8; ++ft)
        cadd[ft] = (ft < 4) ? crel[(ft & 3) * 16 + r] : croot[(ft & 3) * 16 + r];

    const int totalWaves = (gridDim.x * blockDim.x) >> 6;
    for (int tile = wid; tile < NT; tile += totalWaves) {
        const int n0 = tile * 16;
        short8v A0 = *(const short8v*)&u1b[(n0 + r) * 64 + 8 * q];
        short8v A1 = *(const short8v*)&u1b[(n0 + r) * 64 + 32 + 8 * q];
        #pragma unroll
        for (int ft = 0; ft < 8; ++ft) {
            f32x4v d = {0.f, 0.f, 0.f, 0.f};
            d = __builtin_amdgcn_mfma_f32_16x16x32_bf16(A0, Bf[0][ft], d, 0, 0, 0);
            d = __builtin_amdgcn_mfma_f32_16x16x32_bf16(A1, Bf[1][ft], d, 0, 0, 0);
            unsigned short* O = (ft < 4) ? tb : pb;
            const int f0 = (ft & 3) * 16;
            const float ca = cadd[ft];
            #pragma unroll
            for (int rr = 0; rr < 4; ++rr) {
                int n = n0 + 4 * q + rr;
                O[n * 64 + f0 + r] = f2bf(d[rr] + ca);
            }
        }
    }
}

// ---- gather+pool (round-7 static inner loop): u2[n] = relu(sum_src t[src] + p[n]);
// ---- BN2 stats; pooled sums. Wave per node-chunk, lane = feature, 16-deep pipeline. ----
__global__ __launch_bounds__(256, 8) void gatherpool_kernel(
    const unsigned short* __restrict__ tb, const unsigned short* __restrict__ pb,
    const int* __restrict__ rowstart, const int* __restrict__ srcs,
    const int* __restrict__ membership,
    float* __restrict__ pooled, float* __restrict__ sums, float* __restrict__ sumsq,
    int N, int chunk)
{
    __shared__ float red[4][64];
    const int tid = threadIdx.x;
    const int w = tid >> 6, f = tid & 63;
    const int gw = __builtin_amdgcn_readfirstlane(blockIdx.x * 4 + w);
    const int n0 = gw * chunk;
    const int n1 = min(N, n0 + chunk);
    float ps = 0.f, pq = 0.f, pacc = 0.f;
    int curg = (n0 < N) ? membership[n0] : -1;

    for (int n = n0; n < n1; ++n) {
        int s0 = rowstart[n], s1 = rowstart[n + 1];
        float acc = bfu(pb[n * 64 + f]);
        int j = s0;
        for (; j + 15 < s1; j += 16) {
            float vs[16];
            #pragma unroll
            for (int q = 0; q < 16; ++q)
                vs[q] = bfu(tb[srcs[j + q] * 64 + f]);
            float sA = ((vs[0] + vs[1]) + (vs[2] + vs[3])) + ((vs[4] + vs[5]) + (vs[6] + vs[7]));
            float sB = ((vs[8] + vs[9]) + (vs[10] + vs[11])) + ((vs[12] + vs[13]) + (vs[14] + vs[15]));
            acc += sA + sB;
        }
        for (; j + 3 < s1; j += 4) {
            float v0 = bfu(tb[srcs[j + 0] * 64 + f]);
            float v1 = bfu(tb[srcs[j + 1] * 64 + f]);
            float v2 = bfu(tb[srcs[j + 2] * 64 + f]);
            float v3 = bfu(tb[srcs[j + 3] * 64 + f]);
            acc += (v0 + v1) + (v2 + v3);
        }
        for (; j < s1; ++j) acc += bfu(tb[srcs[j] * 64 + f]);

        acc = fmaxf(acc, 0.f);
        ps += acc; pq += acc * acc;

        int g = membership[n];
        if (g != curg) {
            atomAddG(&pooled[curg * 64 + f], pacc);
            pacc = 0.f;
            curg = g;
        }
        pacc += acc;
    }
    if (curg >= 0) atomAddG(&pooled[curg * 64 + f], pacc);

    red[w][f] = ps;
    __syncthreads();
    if (w == 0) atomAddG(&sums[f], red[0][f] + red[1][f] + red[2][f] + red[3][f]);
    __syncthreads();
    red[w][f] = pq;
    __syncthreads();
    if (w == 0) atomAddG(&sumsq[f], red[0][f] + red[1][f] + red[2][f] + red[3][f]);
}

// ---- head fused: BN2 inline; pm = BN2(pooled/cnt); z = BN3(relu(pm@W_fc1+b));
// ---- out = z@W_fc2 + b_fc2 ----
__global__ __launch_bounds__(1024) void fc12_kernel(
    const float* __restrict__ pooled, const int* __restrict__ gstart,
    const float* __restrict__ sums2, const float* __restrict__ sumsq2,
    const float* __restrict__ g2, const float* __restrict__ b2, float invn,
    const float* __restrict__ W_fc1, const float* __restrict__ b_fc1,
    const float* __restrict__ g3, const float* __restrict__ b3,
    const float* __restrict__ W_fc2, const float* __restrict__ b_fc2,
    float* __restrict__ z, float* __restrict__ out)
{
    __shared__ float pm[4096];
    __shared__ float reds[4][256], redq[4][256];
    __shared__ float lsc[256], lsh[256];
    __shared__ float sc2[64], sh2[64];
    const int t = threadIdx.x;
    if (t < 64) {
        float m = sums2[t] * invn;
        float v = sumsq2[t] * invn - m * m;
        float sc = g2[t] * rsqrtf(v + EPSV);
        sc2[t] = sc;
        sh2[t] = b2[t] - m * sc;
    }
    __syncthreads();
    for (int i = t; i < 4096; i += 1024) {
        int g = i >> 6, f = i & 63;
        float c = fmaxf((float)(gstart[g + 1] - gstart[g]), 1.0f);
        pm[i] = fmaf(pooled[i] / c, sc2[f], sh2[f]);
    }
    __syncthreads();
    const int col = t & 255, grp = t >> 8;
    float acc[16];
    const float bc = b_fc1[col];
    #pragma unroll
    for (int g = 0; g < 16; ++g) acc[g] = bc;
    for (int k = 0; k < 64; ++k) {
        float wv = W_fc1[k * 256 + col];
        #pragma unroll
        for (int g = 0; g < 16; ++g)
            acc[g] = fmaf(pm[(grp * 16 + g) * 64 + k], wv, acc[g]);
    }
    float s = 0.f, q = 0.f;
    #pragma unroll
    for (int g = 0; g < 16; ++g) {
        acc[g] = fmaxf(acc[g], 0.f);
        s += acc[g]; q += acc[g] * acc[g];
    }
    reds[grp][col] = s; redq[grp][col] = q;
    __syncthreads();
    if (grp == 0) {
        float S = reds[0][col] + reds[1][col] + reds[2][col] + reds[3][col];
        float Q = redq[0][col] + redq[1][col] + redq[2][col] + redq[3][col];
        float m = S * (1.0f / 64.0f);
        float v = Q * (1.0f / 64.0f) - m * m;
        float sc = g3[col] * rsqrtf(v + EPSV);
        lsc[col] = sc;
        lsh[col] = b3[col] - m * sc;
    }
    __syncthreads();
    float sc = lsc[col], sh = lsh[col];
    #pragma unroll
    for (int g = 0; g < 16; ++g)
        z[(grp * 16 + g) * 256 + col] = fmaf(acc[g], sc, sh);
    __syncthreads();
    if (t < 640) {
        int g = t / 10, o = t % 10;
        float a = b_fc2[o];
        for (int c = 0; c < 256; ++c)
            a = fmaf(z[g * 256 + c], W_fc2[c * 10 + o], a);
        out[g * 10 + o] = a;
    }
}

extern "C" void kernel_launch(void* const* d_in, const int* in_sizes, int n_in,
                              void* d_out, int out_size, void* d_ws, size_t ws_size,
                              hipStream_t stream) {
    const int N = 100000, E = 1600000;

    const float* x          = (const float*)d_in[0];
    const int*   membership = (const int*)d_in[1];
    const int*   edges      = (const int*)d_in[2];
    const float* W_rel1     = (const float*)d_in[3];
    const float* b_rel1     = (const float*)d_in[4];
    const float* W_root1    = (const float*)d_in[5];
    const float* W_rel2     = (const float*)d_in[6];
    const float* b_rel2     = (const float*)d_in[7];
    const float* W_root2    = (const float*)d_in[8];
    const float* g1         = (const float*)d_in[9];
    const float* b1         = (const float*)d_in[10];
    const float* g2         = (const float*)d_in[11];
    const float* b2         = (const float*)d_in[12];
    const float* W_fc1      = (const float*)d_in[13];
    const float* b_fc1      = (const float*)d_in[14];
    const float* g3         = (const float*)d_in[15];
    const float* b3         = (const float*)d_in[16];
    const float* W_fc2      = (const float*)d_in[17];
    const float* b_fc2      = (const float*)d_in[18];

    // workspace layout (4B elements)
    int*   wsi      = (int*)d_ws;
    float* wsf      = (float*)d_ws;
    int*   gbcnt    = wsi + 0;        // 784
    float* stats    = wsf + 784;      // 512
    float* pooled   = wsf + 1296;     // 4096
    int*   bbase    = wsi + 5392;     // 800 (NB+1)
    int*   gcursor  = wsi + 6192;     // 784
    int*   gstart   = wsi + 6976;     // 128
    int*   rowstart = wsi + 7104;     // 100064
    int*   pk       = wsi + 107168;   // 1600000
    int*   srcs     = wsi + 1707168;  // 1600000
    unsigned short* u1b = (unsigned short*)(wsf + 3607200);   // 3200000 f
    unsigned short* tb  = (unsigned short*)(wsf + 6807200);   // 3200000 f
    unsigned short* pb  = (unsigned short*)(wsf + 10007200);  // 3200000 f
    unsigned short* wrelp  = (unsigned short*)(wsf + 13207200); // 2048 f
    unsigned short* wrootp = (unsigned short*)(wsf + 13209248); // 2048 f
    float* crel     = wsf + 13211296; // 64
    float* croot    = wsf + 13211360; // 64
    float* z        = wsf + 13211424; // 16384
    float* xp       = wsf + 13227808; // 400032

    float* sums1  = stats + 0;
    float* sumsq1 = stats + 64;
    float* sums2  = stats + 128;
    float* sumsq2 = stats + 192;

    hipMemsetAsync(d_ws, 0, (size_t)(784 + 512 + 4096) * 4, stream);

    // CSR build (xpad + bounds fused into bhist; layer1 fused into bsort)
    const int EB = (E + 4095) / 4096;    // 391
    const int EB2 = (E + 8191) / 8192;   // 196
    bhist_kernel<<<EB, 256, 0, stream>>>(edges, gbcnt, x, xp, membership, gstart, E, N);
    bscan_kernel<<<1, 256, 0, stream>>>(gbcnt, bbase, gcursor, E);
    bfill_kernel<<<EB2, 256, 0, stream>>>(edges, gcursor, pk, E);
    bsort_kernel<<<NB, 256, 0, stream>>>(pk, bbase, xp, W_rel1, b_rel1, W_root1,
                                         rowstart, srcs, u1b, sums1, sumsq1, N, E);

    // fused BN1 scale/shift + weight fold, then MFMA transform
    bnfold_kernel<<<1, 256, 0, stream>>>(sums1, sumsq1, g1, b1,
                                         W_rel2, W_root2, b_rel2,
                                         wrelp, wrootp, crel, croot, 1.0f / N);
    mfma_transform_kernel<<<512, 256, 0, stream>>>(
        u1b, wrelp, wrootp, crel, croot, tb, pb, N / 16);

    // streaming bf16 gather + pool (finer static chunks for tail smoothing)
    {
        const int GRID2 = 4096;
        int chunk = (N + GRID2 * 4 - 1) / (GRID2 * 4);  // 7
        gatherpool_kernel<<<GRID2, 256, 0, stream>>>(
            tb, pb, rowstart, srcs, membership, pooled, sums2, sumsq2, N, chunk);
    }

    // fused head (BN2 inline)
    fc12_kernel<<<1, 1024, 0, stream>>>(pooled, gstart, sums2, sumsq2, g2, b2, 1.0f / N,
                                        W_fc1, b_fc1, g3, b3, W_fc2, b_fc2,
                                        z, (float*)d_out);
}

// Round 14
// 233.806 us; speedup vs baseline: 1.1984x; 1.1984x over previous
//
#include <hip/hip_runtime.h>
#include <hip/hip_bf16.h>

#define EPSV 1e-5f
#define BKT 128            // nodes per bucket
#define NB  782            // ceil(100000/128)
#define LPK 4096           // LDS pk cache per bucket (mean 2048, +45 sigma safe)

typedef __hip_bfloat16 bf16;
typedef __attribute__((ext_vector_type(8))) short short8v;
typedef __attribute__((ext_vector_type(4))) float f32x4v;

__device__ inline void atomAddG(float* p, float v) { unsafeAtomicAdd(p, v); }
__device__ inline unsigned short f2bf(float v) {
    bf16 h = __float2bfloat16(v);
    return *reinterpret_cast<unsigned short*>(&h);
}
__device__ inline float bfu(unsigned short u) {
    return __uint_as_float(((unsigned int)u) << 16);
}

// ---- bucket histogram (782 bins) + fused xpad + fused graph-bounds ----
__global__ __launch_bounds__(256) void bhist_kernel(
    const int* __restrict__ edges, int* __restrict__ gbcnt,
    const float* __restrict__ x, float* __restrict__ xp,
    const int* __restrict__ membership, int* __restrict__ gstart, int E, int N)
{
    __shared__ int lh[NB];
    const int t = threadIdx.x;
    for (int i = t; i < NB; i += 256) lh[i] = 0;
    // fused xpad + bounds: this grid (391x256 = 100096) covers N+1
    {
        int n = blockIdx.x * 256 + t;
        if (n < N) {
            float4 v;
            v.x = x[n * 3 + 0]; v.y = x[n * 3 + 1]; v.z = x[n * 3 + 2]; v.w = 0.f;
            *(float4*)&xp[n * 4] = v;
        }
        if (n <= N) {
            int mp = (n == 0) ? -1 : membership[n - 1];
            int mc = (n == N) ? 64 : membership[n];
            for (int g = mp + 1; g <= mc; ++g) gstart[g] = n;
        }
    }
    __syncthreads();
    const int base = blockIdx.x * 4096;
    #pragma unroll
    for (int i = 0; i < 16; ++i) {
        int e = base + i * 256 + t;
        if (e < E) atomicAdd(&lh[edges[E + e] >> 7], 1);
    }
    __syncthreads();
    for (int i = t; i < NB; i += 256) {
        int c = lh[i];
        if (c) atomicAdd(&gbcnt[i], c);
    }
}

// ------- bucket scan (single block): bbase exclusive + cursor copy -------
__global__ __launch_bounds__(256) void bscan_kernel(
    const int* __restrict__ gbcnt, int* __restrict__ bbase,
    int* __restrict__ gcursor, int E)
{
    __shared__ int l[256];
    const int t = threadIdx.x;
    int b0 = t * 4;
    int v0 = (b0 + 0 < NB) ? gbcnt[b0 + 0] : 0;
    int v1 = (b0 + 1 < NB) ? gbcnt[b0 + 1] : 0;
    int v2 = (b0 + 2 < NB) ? gbcnt[b0 + 2] : 0;
    int v3 = (b0 + 3 < NB) ? gbcnt[b0 + 3] : 0;
    int tot = v0 + v1 + v2 + v3;
    l[t] = tot;
    __syncthreads();
    for (int o = 1; o < 256; o <<= 1) {
        int add = (t >= o) ? l[t - o] : 0;
        __syncthreads();
        l[t] += add;
        __syncthreads();
    }
    int off = l[t] - tot;
    if (b0 + 0 < NB) { bbase[b0 + 0] = off;                gcursor[b0 + 0] = off; }
    if (b0 + 1 < NB) { bbase[b0 + 1] = off + v0;           gcursor[b0 + 1] = off + v0; }
    if (b0 + 2 < NB) { bbase[b0 + 2] = off + v0 + v1;      gcursor[b0 + 2] = off + v0 + v1; }
    if (b0 + 3 < NB) { bbase[b0 + 3] = off + v0 + v1 + v2; gcursor[b0 + 3] = off + v0 + v1 + v2; }
    if (t == 0) bbase[NB] = E;
}

// ------- bucket fill: pk = (src<<7)|(dst&127), 8192 edges/block -------
__global__ __launch_bounds__(256) void bfill_kernel(
    const int* __restrict__ edges, int* __restrict__ gcursor,
    int* __restrict__ pk, int E)
{
    __shared__ int lh[NB];
    __shared__ int lbase[NB];
    const int t = threadIdx.x;
    for (int i = t; i < NB; i += 256) lh[i] = 0;
    __syncthreads();
    const int base = blockIdx.x * 8192;
    int dv[32];
    #pragma unroll
    for (int i = 0; i < 32; ++i) {
        int e = base + i * 256 + t;
        dv[i] = (e < E) ? edges[E + e] : -1;
        if (dv[i] >= 0) atomicAdd(&lh[dv[i] >> 7], 1);
    }
    __syncthreads();
    for (int i = t; i < NB; i += 256) {
        int c = lh[i];
        lbase[i] = c ? atomicAdd(&gcursor[i], c) : 0;
        lh[i] = 0;
    }
    __syncthreads();
    #pragma unroll
    for (int i = 0; i < 32; ++i) {
        int e = base + i * 256 + t;
        if (dv[i] >= 0) {
            int s = edges[e];
            int b = dv[i] >> 7;
            int pos = lbase[b] + atomicAdd(&lh[b], 1);
            pk[pos] = (s << 7) | (dv[i] & 127);
        }
    }
}

// ---- per-bucket fine sort + fused x-gather + FUSED LAYER 1:
// ---- CSR rowstart + srcs; u1b = bf16(relu(agg@W_rel1+b+x@W_root1)); BN1 stats. ----
__global__ __launch_bounds__(256) void bsort_kernel(
    const int* __restrict__ pk, const int* __restrict__ bbase,
    const float* __restrict__ xp,
    const float* __restrict__ W_rel1, const float* __restrict__ b_rel1,
    const float* __restrict__ W_root1,
    int* __restrict__ rowstart, int* __restrict__ srcs,
    unsigned short* __restrict__ u1b, float* __restrict__ sums, float* __restrict__ sumsq,
    int N, int E)
{
    __shared__ int lcnt[BKT];
    __shared__ int lscan[BKT];
    __shared__ float accx[BKT * 4];
    __shared__ int lpk[LPK];
    __shared__ float red[4][64];
    const int t = threadIdx.x;
    const int b = blockIdx.x;
    const int e0 = bbase[b], e1 = bbase[b + 1];
    const int cnt = e1 - e0;
    if (t < BKT) lcnt[t] = 0;
    for (int i = t; i < BKT * 4; i += 256) accx[i] = 0.f;
    for (int i = t; i < cnt && i < LPK; i += 256) lpk[i] = pk[e0 + i];
    __syncthreads();
    for (int i = t; i < cnt; i += 256) {
        int v = (i < LPK) ? lpk[i] : pk[e0 + i];
        atomicAdd(&lcnt[v & 127], 1);
    }
    __syncthreads();
    if (t < BKT) lscan[t] = lcnt[t];
    __syncthreads();
    for (int o = 1; o < BKT; o <<= 1) {
        int add = (t < BKT && t >= o) ? lscan[t - o] : 0;
        __syncthreads();
        if (t < BKT) lscan[t] += add;
        __syncthreads();
    }
    const int n0 = b * BKT;
    if (t < BKT) {
        int excl = lscan[t] - lcnt[t];
        lscan[t] = excl;
        int n = n0 + t;
        if (n <= N) rowstart[n] = e0 + excl;   // last bucket's t=32 writes rowstart[N]=E
        lcnt[t] = 0;
    }
    __syncthreads();
    for (int i = t; i < cnt; i += 256) {
        int v = (i < LPK) ? lpk[i] : pk[e0 + i];
        int ld = v & 127;
        int s = v >> 7;
        int pos = atomicAdd(&lcnt[ld], 1);
        srcs[e0 + lscan[ld] + pos] = s;
        float4 xv = *(const float4*)&xp[s * 4];
        atomicAdd(&accx[ld * 4 + 0], xv.x);
        atomicAdd(&accx[ld * 4 + 1], xv.y);
        atomicAdd(&accx[ld * 4 + 2], xv.z);
    }
    __syncthreads();

    // fused layer 1: u1 = relu(agg@W_rel1 + b_rel1 + x@W_root1) -> bf16, + stats
    const int f = t & 63, r4 = t >> 6;
    const float wr0 = W_rel1[f], wr1 = W_rel1[64 + f], wr2 = W_rel1[128 + f];
    const float wo0 = W_root1[f], wo1 = W_root1[64 + f], wo2 = W_root1[128 + f];
    const float bb = b_rel1[f];
    float ps = 0.f, pq = 0.f;
    for (int i = r4; i < BKT; i += 4) {
        int n = n0 + i;
        if (n < N) {
            float4 xv = *(const float4*)&xp[n * 4];
            float a0 = accx[i * 4 + 0], a1 = accx[i * 4 + 1], a2 = accx[i * 4 + 2];
            float v = bb;
            v = fmaf(a0, wr0, v); v = fmaf(a1, wr1, v); v = fmaf(a2, wr2, v);
            v = fmaf(xv.x, wo0, v); v = fmaf(xv.y, wo1, v); v = fmaf(xv.z, wo2, v);
            v = fmaxf(v, 0.f);
            u1b[n * 64 + f] = f2bf(v);
            ps += v; pq += v * v;
        }
    }
    red[r4][f] = ps;
    __syncthreads();
    if (r4 == 0) atomAddG(&sums[f], red[0][f] + red[1][f] + red[2][f] + red[3][f]);
    __syncthreads();
    red[r4][f] = pq;
    __syncthreads();
    if (r4 == 0) atomAddG(&sumsq[f], red[0][f] + red[1][f] + red[2][f] + red[3][f]);
}

// ---- fused BN1-stats + weight fold: W' = bf16(diag(sc1)W), c = sh1·W (+b_rel2) ----
__global__ __launch_bounds__(256) void bnfold_kernel(
    const float* __restrict__ sums1, const float* __restrict__ sumsq1,
    const float* __restrict__ g1, const float* __restrict__ b1,
    const float* __restrict__ W_rel2, const float* __restrict__ W_root2,
    const float* __restrict__ b_rel2,
    unsigned short* __restrict__ wrelp, unsigned short* __restrict__ wrootp,
    float* __restrict__ crel, float* __restrict__ croot, float invn)
{
    __shared__ float lsc[64], lsh[64];
    __shared__ float r1[4][64], r2[4][64];
    const int t = threadIdx.x, f = t & 63, kg = t >> 6;
    if (t < 64) {
        float m = sums1[t] * invn;
        float v = sumsq1[t] * invn - m * m;
        float sc = g1[t] * rsqrtf(v + EPSV);
        lsc[t] = sc;
        lsh[t] = b1[t] - m * sc;
    }
    __syncthreads();
    float c1 = 0.f, c2 = 0.f;
    for (int k = kg * 16; k < kg * 16 + 16; ++k) {
        float sc = lsc[k], sh = lsh[k];
        float w1 = W_rel2[k * 64 + f], w2 = W_root2[k * 64 + f];
        wrelp[k * 64 + f] = f2bf(sc * w1);
        wrootp[k * 64 + f] = f2bf(sc * w2);
        c1 = fmaf(sh, w1, c1); c2 = fmaf(sh, w2, c2);
    }
    r1[kg][f] = c1; r2[kg][f] = c2;
    __syncthreads();
    if (kg == 0) {
        crel[f]  = r1[0][f] + r1[1][f] + r1[2][f] + r1[3][f];
        croot[f] = r2[0][f] + r2[1][f] + r2[2][f] + r2[3][f] + b_rel2[f];
    }
}

// ---- MFMA transform: t = bf16(u1b@W_rel' + crel); p = bf16(u1b@W_root' + croot) ----
__global__ __launch_bounds__(256) void mfma_transform_kernel(
    const unsigned short* __restrict__ u1b,
    const unsigned short* __restrict__ wrelp, const unsigned short* __restrict__ wrootp,
    const float* __restrict__ crel, const float* __restrict__ croot,
    unsigned short* __restrict__ tb, unsigned short* __restrict__ pb, int NT)
{
    const int wid = (blockIdx.x * blockDim.x + threadIdx.x) >> 6;
    const int lane = threadIdx.x & 63;
    const int q = lane >> 4, r = lane & 15;

    short8v Bf[2][8];
    float cadd[8];
    #pragma unroll
    for (int kc = 0; kc < 2; ++kc) {
        #pragma unroll
        for (int ft = 0; ft < 8; ++ft) {
            const unsigned short* W = (ft < 4) ? wrelp : wrootp;
            const int f0 = (ft & 3) * 16;
            short8v bb;
            #pragma unroll
            for (int j = 0; j < 8; ++j) {
                int k = 32 * kc + 8 * q + j;
                bb[j] = (short)W[k * 64 + f0 + r];
            }
            Bf[kc][ft] = bb;
        }
    }
    #pragma unroll
    for (int ft = 0; ft < 8; ++ft)
        cadd[ft] = (ft < 4) ? crel[(ft & 3) * 16 + r] : croot[(ft & 3) * 16 + r];

    const int totalWaves = (gridDim.x * blockDim.x) >> 6;
    for (int tile = wid; tile < NT; tile += totalWaves) {
        const int n0 = tile * 16;
        short8v A0 = *(const short8v*)&u1b[(n0 + r) * 64 + 8 * q];
        short8v A1 = *(const short8v*)&u1b[(n0 + r) * 64 + 32 + 8 * q];
        #pragma unroll
        for (int ft = 0; ft < 8; ++ft) {
            f32x4v d = {0.f, 0.f, 0.f, 0.f};
            d = __builtin_amdgcn_mfma_f32_16x16x32_bf16(A0, Bf[0][ft], d, 0, 0, 0);
            d = __builtin_amdgcn_mfma_f32_16x16x32_bf16(A1, Bf[1][ft], d, 0, 0, 0);
            unsigned short* O = (ft < 4) ? tb : pb;
            const int f0 = (ft & 3) * 16;
            const float ca = cadd[ft];
            #pragma unroll
            for (int rr = 0; rr < 4; ++rr) {
                int n = n0 + 4 * q + rr;
                O[n * 64 + f0 + r] = f2bf(d[rr] + ca);
            }
        }
    }
}

// ---- gather+pool (round-7 static, GRID 2048): u2[n] = relu(sum_src t[src] + p[n]);
// ---- BN2 stats; pooled sums. Wave per node-chunk, lane = feature, 16-deep pipeline. ----
__global__ __launch_bounds__(256, 8) void gatherpool_kernel(
    const unsigned short* __restrict__ tb, const unsigned short* __restrict__ pb,
    const int* __restrict__ rowstart, const int* __restrict__ srcs,
    const int* __restrict__ membership,
    float* __restrict__ pooled, float* __restrict__ sums, float* __restrict__ sumsq,
    int N, int chunk)
{
    __shared__ float red[4][64];
    const int tid = threadIdx.x;
    const int w = tid >> 6, f = tid & 63;
    const int gw = __builtin_amdgcn_readfirstlane(blockIdx.x * 4 + w);
    const int n0 = gw * chunk;
    const int n1 = min(N, n0 + chunk);
    float ps = 0.f, pq = 0.f, pacc = 0.f;
    int curg = (n0 < N) ? membership[n0] : -1;

    for (int n = n0; n < n1; ++n) {
        int s0 = rowstart[n], s1 = rowstart[n + 1];
        float acc = bfu(pb[n * 64 + f]);
        int j = s0;
        for (; j + 15 < s1; j += 16) {
            float vs[16];
            #pragma unroll
            for (int q = 0; q < 16; ++q)
                vs[q] = bfu(tb[srcs[j + q] * 64 + f]);
            float sA = ((vs[0] + vs[1]) + (vs[2] + vs[3])) + ((vs[4] + vs[5]) + (vs[6] + vs[7]));
            float sB = ((vs[8] + vs[9]) + (vs[10] + vs[11])) + ((vs[12] + vs[13]) + (vs[14] + vs[15]));
            acc += sA + sB;
        }
        for (; j + 3 < s1; j += 4) {
            float v0 = bfu(tb[srcs[j + 0] * 64 + f]);
            float v1 = bfu(tb[srcs[j + 1] * 64 + f]);
            float v2 = bfu(tb[srcs[j + 2] * 64 + f]);
            float v3 = bfu(tb[srcs[j + 3] * 64 + f]);
            acc += (v0 + v1) + (v2 + v3);
        }
        for (; j < s1; ++j) acc += bfu(tb[srcs[j] * 64 + f]);

        acc = fmaxf(acc, 0.f);
        ps += acc; pq += acc * acc;

        int g = membership[n];
        if (g != curg) {
            atomAddG(&pooled[curg * 64 + f], pacc);
            pacc = 0.f;
            curg = g;
        }
        pacc += acc;
    }
    if (curg >= 0) atomAddG(&pooled[curg * 64 + f], pacc);

    red[w][f] = ps;
    __syncthreads();
    if (w == 0) atomAddG(&sums[f], red[0][f] + red[1][f] + red[2][f] + red[3][f]);
    __syncthreads();
    red[w][f] = pq;
    __syncthreads();
    if (w == 0) atomAddG(&sumsq[f], red[0][f] + red[1][f] + red[2][f] + red[3][f]);
}

// ---- head fused: BN2 inline; pm = BN2(pooled/cnt); z = BN3(relu(pm@W_fc1+b));
// ---- out = z@W_fc2 + b_fc2 ----
__global__ __launch_bounds__(1024) void fc12_kernel(
    const float* __restrict__ pooled, const int* __restrict__ gstart,
    const float* __restrict__ sums2, const float* __restrict__ sumsq2,
    const float* __restrict__ g2, const float* __restrict__ b2, float invn,
    const float* __restrict__ W_fc1, const float* __restrict__ b_fc1,
    const float* __restrict__ g3, const float* __restrict__ b3,
    const float* __restrict__ W_fc2, const float* __restrict__ b_fc2,
    float* __restrict__ z, float* __restrict__ out)
{
    __shared__ float pm[4096];
    __shared__ float reds[4][256], redq[4][256];
    __shared__ float lsc[256], lsh[256];
    __shared__ float sc2[64], sh2[64];
    const int t = threadIdx.x;
    if (t < 64) {
        float m = sums2[t] * invn;
        float v = sumsq2[t] * invn - m * m;
        float sc = g2[t] * rsqrtf(v + EPSV);
        sc2[t] = sc;
        sh2[t] = b2[t] - m * sc;
    }
    __syncthreads();
    for (int i = t; i < 4096; i += 1024) {
        int g = i >> 6, f = i & 63;
        float c = fmaxf((float)(gstart[g + 1] - gstart[g]), 1.0f);
        pm[i] = fmaf(pooled[i] / c, sc2[f], sh2[f]);
    }
    __syncthreads();
    const int col = t & 255, grp = t >> 8;
    float acc[16];
    const float bc = b_fc1[col];
    #pragma unroll
    for (int g = 0; g < 16; ++g) acc[g] = bc;
    for (int k = 0; k < 64; ++k) {
        float wv = W_fc1[k * 256 + col];
        #pragma unroll
        for (int g = 0; g < 16; ++g)
            acc[g] = fmaf(pm[(grp * 16 + g) * 64 + k], wv, acc[g]);
    }
    float s = 0.f, q = 0.f;
    #pragma unroll
    for (int g = 0; g < 16; ++g) {
        acc[g] = fmaxf(acc[g], 0.f);
        s += acc[g]; q += acc[g] * acc[g];
    }
    reds[grp][col] = s; redq[grp][col] = q;
    __syncthreads();
    if (grp == 0) {
        float S = reds[0][col] + reds[1][col] + reds[2][col] + reds[3][col];
        float Q = redq[0][col] + redq[1][col] + redq[2][col] + redq[3][col];
        float m = S * (1.0f / 64.0f);
        float v = Q * (1.0f / 64.0f) - m * m;
        float sc = g3[col] * rsqrtf(v + EPSV);
        lsc[col] = sc;
        lsh[col] = b3[col] - m * sc;
    }
    __syncthreads();
    float sc = lsc[col], sh = lsh[col];
    #pragma unroll
    for (int g = 0; g < 16; ++g)
        z[(grp * 16 + g) * 256 + col] = fmaf(acc[g], sc, sh);
    __syncthreads();
    if (t < 640) {
        int g = t / 10, o = t % 10;
        float a = b_fc2[o];
        for (int c = 0; c < 256; ++c)
            a = fmaf(z[g * 256 + c], W_fc2[c * 10 + o], a);
        out[g * 10 + o] = a;
    }
}

extern "C" void kernel_launch(void* const* d_in, const int* in_sizes, int n_in,
                              void* d_out, int out_size, void* d_ws, size_t ws_size,
                              hipStream_t stream) {
    const int N = 100000, E = 1600000;

    const float* x          = (const float*)d_in[0];
    const int*   membership = (const int*)d_in[1];
    const int*   edges      = (const int*)d_in[2];
    const float* W_rel1     = (const float*)d_in[3];
    const float* b_rel1     = (const float*)d_in[4];
    const float* W_root1    = (const float*)d_in[5];
    const float* W_rel2     = (const float*)d_in[6];
    const float* b_rel2     = (const float*)d_in[7];
    const float* W_root2    = (const float*)d_in[8];
    const float* g1         = (const float*)d_in[9];
    const float* b1         = (const float*)d_in[10];
    const float* g2         = (const float*)d_in[11];
    const float* b2         = (const float*)d_in[12];
    const float* W_fc1      = (const float*)d_in[13];
    const float* b_fc1      = (const float*)d_in[14];
    const float* g3         = (const float*)d_in[15];
    const float* b3         = (const float*)d_in[16];
    const float* W_fc2      = (const float*)d_in[17];
    const float* b_fc2      = (const float*)d_in[18];

    // workspace layout (4B elements)
    int*   wsi      = (int*)d_ws;
    float* wsf      = (float*)d_ws;
    int*   gbcnt    = wsi + 0;        // 784
    float* stats    = wsf + 784;      // 512
    float* pooled   = wsf + 1296;     // 4096
    int*   bbase    = wsi + 5392;     // 800 (NB+1)
    int*   gcursor  = wsi + 6192;     // 784
    int*   gstart   = wsi + 6976;     // 128
    int*   rowstart = wsi + 7104;     // 100064
    int*   pk       = wsi + 107168;   // 1600000
    int*   srcs     = wsi + 1707168;  // 1600000
    unsigned short* u1b = (unsigned short*)(wsf + 3607200);   // 3200000 f
    unsigned short* tb  = (unsigned short*)(wsf + 6807200);   // 3200000 f
    unsigned short* pb  = (unsigned short*)(wsf + 10007200);  // 3200000 f
    unsigned short* wrelp  = (unsigned short*)(wsf + 13207200); // 2048 f
    unsigned short* wrootp = (unsigned short*)(wsf + 13209248); // 2048 f
    float* crel     = wsf + 13211296; // 64
    float* croot    = wsf + 13211360; // 64
    float* z        = wsf + 13211424; // 16384
    float* xp       = wsf + 13227808; // 400032

    float* sums1  = stats + 0;
    float* sumsq1 = stats + 64;
    float* sums2  = stats + 128;
    float* sumsq2 = stats + 192;

    hipMemsetAsync(d_ws, 0, (size_t)(784 + 512 + 4096) * 4, stream);

    // CSR build (xpad + bounds fused into bhist; layer1 fused into bsort)
    const int EB = (E + 4095) / 4096;    // 391
    const int EB2 = (E + 8191) / 8192;   // 196
    bhist_kernel<<<EB, 256, 0, stream>>>(edges, gbcnt, x, xp, membership, gstart, E, N);
    bscan_kernel<<<1, 256, 0, stream>>>(gbcnt, bbase, gcursor, E);
    bfill_kernel<<<EB2, 256, 0, stream>>>(edges, gcursor, pk, E);
    bsort_kernel<<<NB, 256, 0, stream>>>(pk, bbase, xp, W_rel1, b_rel1, W_root1,
                                         rowstart, srcs, u1b, sums1, sumsq1, N, E);

    // fused BN1 scale/shift + weight fold, then MFMA transform
    bnfold_kernel<<<1, 256, 0, stream>>>(sums1, sumsq1, g1, b1,
                                         W_rel2, W_root2, b_rel2,
                                         wrelp, wrootp, crel, croot, 1.0f / N);
    mfma_transform_kernel<<<512, 256, 0, stream>>>(
        u1b, wrelp, wrootp, crel, croot, tb, pb, N / 16);

    // streaming bf16 gather + pool (capacity-matched static chunks: 2048 blocks)
    {
        const int GRID2 = 2048;
        int chunk = (N + GRID2 * 4 - 1) / (GRID2 * 4);  // 13
        gatherpool_kernel<<<GRID2, 256, 0, stream>>>(
            tb, pb, rowstart, srcs, membership, pooled, sums2, sumsq2, N, chunk);
    }

    // fused head (BN2 inline)
    fc12_kernel<<<1, 1024, 0, stream>>>(pooled, gstart, sums2, sumsq2, g2, b2, 1.0f / N,
                                        W_fc1, b_fc1, g3, b3, W_fc2, b_fc2,
                                        z, (float*)d_out);
}